// Round 6
// baseline (140.473 us; speedup 1.0000x reference)
//
#include <hip/hip_runtime.h>

#define BATCH 32
#define HH 1024
#define WW 1024
#define NPIX (HH * WW)
#define NEROS 10
#define TPS 64                // 16-row tiles per sample (tail kernel)
#define NTILES (BATCH * TPS)  // 2048 (tail grid)
#define T0R 8                 // conv0 tile rows
#define T0PS 128              // conv0 tiles per sample
#define NT0 (BATCH * T0PS)    // 4096 (conv0 grid)
#define FWPS 32               // flag words per sample: uint per 32 rows

__device__ __forceinline__ float4 ld4f(const float* p) {
    return *reinterpret_cast<const float4*>(p);
}

// ---------------- iteration 0: LDS-staged fused bound+conv ----------------
// Block = 8-row tile, 512 threads (8 waves), 40 KB LDS -> 4 blocks/CU (100%
// wave occupancy). Stage rows [ry-1, ry+9) of bound=(pred-tgt)^2 via a flat
// burst of 10 independent coalesced dwordx4 loads per thread (fits <64 VGPR
// so the full burst is in flight), then wave w computes row ry+w from LDS.
// Row written to global only if it contains a nonzero (flag bit set).
__global__ __launch_bounds__(512, 8) void conv0_kernel(
    const float* __restrict__ pred, const float* __restrict__ tgt,
    float* __restrict__ out, unsigned* __restrict__ Fout,
    unsigned* __restrict__ cntOut, unsigned* __restrict__ omin,
    unsigned* __restrict__ omax, double* __restrict__ osum) {
    int blk = blockIdx.x;
    blk = (blk & 7) * (NT0 >> 3) + (blk >> 3);  // XCD swizzle (4096%8==0)
    const int s = blk >> 7, ty = blk & 127, ry = ty << 3;
    const int tid = threadIdx.x, lane = tid & 63, w = tid >> 6;  // w: 0..7
    const size_t sbase = (size_t)s * NPIX;

    __shared__ float sb[10 * 1024];  // 40 KB

    // ---- stage: 10 rows x 1024 px = 2560 float4 slots, 5 per thread ----
    float4 pv[5], tv[5];
#pragma unroll
    for (int i = 0; i < 5; ++i) {
        const int slot = tid + 512 * i;
        const int y = ry - 1 + (slot >> 8);
        if (y >= 0 && y < HH) {
            const size_t idx = sbase + (size_t)y * WW + ((slot & 255) << 2);
            pv[i] = ld4f(pred + idx);
            tv[i] = ld4f(tgt + idx);
        } else {
            pv[i] = make_float4(0.f, 0.f, 0.f, 0.f);
            tv[i] = make_float4(0.f, 0.f, 0.f, 0.f);
        }
    }
#pragma unroll
    for (int i = 0; i < 5; ++i) {
        const int slot = tid + 512 * i;
        float4 b;
        b.x = (pv[i].x - tv[i].x) * (pv[i].x - tv[i].x);
        b.y = (pv[i].y - tv[i].y) * (pv[i].y - tv[i].y);
        b.z = (pv[i].z - tv[i].z) * (pv[i].z - tv[i].z);
        b.w = (pv[i].w - tv[i].w) * (pv[i].w - tv[i].w);
        *reinterpret_cast<float4*>(
            &sb[(slot >> 8) * 1024 + ((slot & 255) << 2)]) = b;
    }
    __syncthreads();

    // ---- compute: wave w handles image row ry+w (LDS rows w, w+1, w+2) ----
    float lmin = 3.4e38f, lmax = 0.f, lsum = 0.f;
    unsigned rowbits = 0u;
    {
        const int y = ry + w;
        float O[16];
        bool nz = false;
#pragma unroll
        for (int q = 0; q < 4; ++q) {
            const int xw = (q << 8) + (lane << 2);
            const float4 U = *(const float4*)&sb[w * 1024 + xw];
            const float4 Cc = *(const float4*)&sb[(w + 1) * 1024 + xw];
            const float4 D = *(const float4*)&sb[(w + 2) * 1024 + xw];
            float lf = __shfl_up(Cc.w, 1);
            if (lane == 0)
                lf = (q > 0) ? sb[(w + 1) * 1024 + (q << 8) - 1] : 0.f;
            float rt = __shfl_down(Cc.x, 1);
            if (lane == 63)
                rt = (q < 3) ? sb[(w + 1) * 1024 + (q << 8) + 256] : 0.f;
            const float cv[4] = {Cc.x, Cc.y, Cc.z, Cc.w};
            const float uv[4] = {U.x, U.y, U.z, U.w};
            const float dv[4] = {D.x, D.y, D.z, D.w};
            const float lvv[4] = {lf, Cc.x, Cc.y, Cc.z};
            const float rvv[4] = {Cc.y, Cc.z, Cc.w, rt};
#pragma unroll
            for (int j = 0; j < 4; ++j) {
                const float conv =
                    0.2f * (uv[j] + dv[j] + cv[j] + lvv[j] + rvv[j]);
                const float er = fmaxf(conv - 0.5f, 0.f);
                O[(q << 2) + j] = er;
                lmin = fminf(lmin, er);
                lmax = fmaxf(lmax, er);
                lsum += er;
                nz = nz || (er > 0.f);
            }
        }
        if (__ballot(nz) != 0ull) {  // wave-uniform: write whole row
            const size_t ob = sbase + (size_t)y * WW;
#pragma unroll
            for (int q = 0; q < 4; ++q)
                *reinterpret_cast<float4*>(out + ob + (q << 8) + (lane << 2)) =
                    make_float4(O[q << 2], O[(q << 2) + 1], O[(q << 2) + 2],
                                O[(q << 2) + 3]);
            rowbits = 1u << w;
        }
    }

    // ---- block reduce (8 waves) ----
#pragma unroll
    for (int off = 32; off > 0; off >>= 1) {
        lmin = fminf(lmin, __shfl_down(lmin, off));
        lmax = fmaxf(lmax, __shfl_down(lmax, off));
        lsum += __shfl_down(lsum, off);
    }
    __shared__ float smn[8], smx[8], ssm[8];
    __shared__ unsigned sfb[8];
    if (lane == 0) {
        smn[w] = lmin;
        smx[w] = lmax;
        ssm[w] = lsum;
        sfb[w] = rowbits;
    }
    __syncthreads();
    if (tid == 0) {
        unsigned fmask = sfb[0];
        float bmn = smn[0], bmx = smx[0], bsm = ssm[0];
#pragma unroll
        for (int i = 1; i < 8; ++i) {
            bmn = fminf(bmn, smn[i]);
            bmx = fmaxf(bmx, smx[i]);
            bsm += ssm[i];
            fmask |= sfb[i];
        }
        if (fmask) {
            atomicOr(&Fout[s * FWPS + (ty >> 2)], fmask << ((ty & 3) * 8));
            atomicAdd(cntOut, 1u);
        }
        atomicMin(&omin[s], __float_as_uint(bmn));
        if (bmx > 0.f) atomicMax(&omax[s], __float_as_uint(bmx));
        if (bsm > 0.f) atomicAdd(&osum[s], (double)bsm);
    }
}

// ---------------- iterations 1..9 (sparse tail) ----------------
// Block = 16-row tile, 4 waves; wave w owns rows [ry+4w, ry+4w+4); lane owns
// 16 px. Flag bit per row (uint per 32 rows): set = row has a nonzero.
// Unflagged rows are exact zeros and their memory is never read.
__global__ __launch_bounds__(256, 4) void convt_kernel(
    const float* __restrict__ in, float* __restrict__ out,
    const unsigned* __restrict__ Fprev, unsigned* __restrict__ Fout,
    const unsigned* __restrict__ cntPrev, unsigned* __restrict__ cntOut,
    const unsigned* __restrict__ pmin, const unsigned* __restrict__ pmax,
    unsigned* __restrict__ omin, unsigned* __restrict__ omax,
    double* __restrict__ osum) {
    if (*cntPrev == 0u) return;  // field died: absorbing state

    int blk = blockIdx.x;
    blk = (blk & 7) * (NTILES >> 3) + (blk >> 3);
    const int s = blk >> 6, ty = blk & 63, ry = ty << 4;
    const int tid = threadIdx.x, lane = tid & 63, w = tid >> 6;
    const int xb = lane << 4;
    const size_t sbase = (size_t)s * NPIX;

    // M: bit (i+1) = row ry+i flagged, i in [-1,16]
    const unsigned* Fs = Fprev + s * FWPS;
    const int w32 = ty >> 1, sh = (ty & 1) * 16;
    const unsigned cur = Fs[w32];
    unsigned M = ((cur >> sh) & 0xFFFFu) << 1;
    if (ty > 0)
        M |= (ty & 1) ? ((cur >> 15) & 1u) : ((Fs[w32 - 1] >> 31) & 1u);
    if (ty < TPS - 1) {
        const unsigned nb = (ty & 1) ? (Fs[w32 + 1] & 1u) : ((cur >> 16) & 1u);
        M |= nb << 17;
    }
    if (M == 0u) {  // nothing in reach: tile output exactly zero
        if (tid == 0) atomicMin(&omin[s], 0u);
        return;
    }

    float a = 1.f, cc = 0.f;
    {
        const float mn = __uint_as_float(pmin[s]);
        const float mx = __uint_as_float(pmax[s]);
        const float ptp = mx - mn;
        if (ptp > 0.f) { a = 1.f / ptp; cc = mn; }
    }

    const int r0 = w << 2;
    float A[16], B[16], C[16], O[16];

    auto loadRow = [&](int y, float* V) {
        const bool ok =
            (y >= 0 && y < HH) && (((M >> (y - ry + 1)) & 1u) != 0u);
        if (!ok) {
#pragma unroll
            for (int j = 0; j < 16; ++j) V[j] = 0.f;
            return;
        }
        const size_t idx = sbase + (size_t)y * WW + xb;
#pragma unroll
        for (int q = 0; q < 4; ++q) {
            const float4 v = ld4f(in + idx + 4 * q);
            V[4 * q + 0] = v.x;
            V[4 * q + 1] = v.y;
            V[4 * q + 2] = v.z;
            V[4 * q + 3] = v.w;
        }
    };

    loadRow(ry + r0 - 1, A);
    loadRow(ry + r0, B);

    float lmin = 3.4e38f, lmax = 0.f, lsum = 0.f;
    unsigned rowbits = 0u;

#pragma unroll
    for (int r = 0; r < 4; ++r) {
        const int y = ry + r0 + r;
        loadRow(y + 1, C);
        const bool act = (((M >> (r0 + r)) & 7u) != 0u);
        if (act) {
            float lfe = __shfl_up(B[15], 1);
            if (lane == 0) lfe = 0.f;
            float rte = __shfl_down(B[0], 1);
            if (lane == 63) rte = 0.f;
            const float vert =
                1.f + (y > 0 ? 1.f : 0.f) + (y < HH - 1 ? 1.f : 0.f);
            bool nz = false;
#pragma unroll
            for (int j = 0; j < 16; ++j) {
                const float lf = (j == 0) ? lfe : B[j - 1];
                const float rt = (j == 15) ? rte : B[j + 1];
                const float conv = 0.2f * (A[j] + C[j] + B[j] + lf + rt);
                const int x = xb + j;
                const float kf = 0.2f * (vert + (x > 0 ? 1.f : 0.f) +
                                         (x < WW - 1 ? 1.f : 0.f));
                const float dil = (conv - cc * kf) * a;
                const float er = fmaxf(dil - 0.5f, 0.f);
                O[j] = er;
                lmin = fminf(lmin, er);
                lmax = fmaxf(lmax, er);
                lsum += er;
                nz = nz || (er > 0.f);
            }
            if (__ballot(nz) != 0ull) {
                const size_t oidx = sbase + (size_t)y * WW + xb;
#pragma unroll
                for (int q = 0; q < 4; ++q)
                    *reinterpret_cast<float4*>(out + oidx + 4 * q) =
                        make_float4(O[4 * q], O[4 * q + 1], O[4 * q + 2],
                                    O[4 * q + 3]);
                rowbits |= 1u << (r0 + r);
            }
        } else {
            lmin = fminf(lmin, 0.f);
        }
#pragma unroll
        for (int j = 0; j < 16; ++j) {
            A[j] = B[j];
            B[j] = C[j];
        }
    }

#pragma unroll
    for (int off = 32; off > 0; off >>= 1) {
        lmin = fminf(lmin, __shfl_down(lmin, off));
        lmax = fmaxf(lmax, __shfl_down(lmax, off));
        lsum += __shfl_down(lsum, off);
    }
    __shared__ float smn[4], smx[4], ssm[4];
    __shared__ unsigned sfb[4];
    if (lane == 0) {
        smn[w] = lmin;
        smx[w] = lmax;
        ssm[w] = lsum;
        sfb[w] = rowbits;
    }
    __syncthreads();
    if (tid == 0) {
        const unsigned fmask = sfb[0] | sfb[1] | sfb[2] | sfb[3];
        float bmn = smn[0], bmx = smx[0], bsm = ssm[0];
#pragma unroll
        for (int i = 1; i < 4; ++i) {
            bmn = fminf(bmn, smn[i]);
            bmx = fmaxf(bmx, smx[i]);
            bsm += ssm[i];
        }
        if (fmask) {
            atomicOr(&Fout[s * FWPS + w32], fmask << sh);
            atomicAdd(cntOut, 1u);
        }
        atomicMin(&omin[s], __float_as_uint(bmn));
        if (bmx > 0.f) atomicMax(&omax[s], __float_as_uint(bmx));
        if (bsm > 0.f) atomicAdd(&osum[s], (double)bsm);
    }
}

__global__ void init_kernel(unsigned* __restrict__ minb,
                            unsigned* __restrict__ maxb,
                            double* __restrict__ sums,
                            unsigned* __restrict__ F,
                            unsigned* __restrict__ cnt) {
    const int i = blockIdx.x * blockDim.x + threadIdx.x;
    if (i < NEROS * BATCH) {
        minb[i] = 0x7f800000u;  // +inf
        maxb[i] = 0u;
        sums[i] = 0.0;
    }
    if (i < NEROS * BATCH * FWPS) F[i] = 0u;
    if (i < NEROS) cnt[i] = 0u;
}

__global__ void final_kernel(const unsigned* __restrict__ minb,
                             const unsigned* __restrict__ maxb,
                             const double* __restrict__ sums,
                             float* __restrict__ out) {
    const int s = threadIdx.x;
    double tot = 0.0;
    if (s < BATCH) {
        for (int k = 0; k < NEROS; ++k) {
            const float mn = __uint_as_float(minb[k * BATCH + s]);
            const float mx = __uint_as_float(maxb[k * BATCH + s]);
            const double sm = sums[k * BATCH + s];
            const float ptp = mx - mn;
            double v;
            if (ptp > 0.f)
                v = (sm - (double)NPIX * (double)mn) / (double)ptp;
            else
                v = sm;
            tot += (double)((k + 1) * (k + 1)) * v;
        }
    }
#pragma unroll
    for (int off = 32; off > 0; off >>= 1) tot += __shfl_down(tot, off);
    if (s == 0) out[0] = (float)(tot / ((double)BATCH * (double)NPIX));
}

extern "C" void kernel_launch(void* const* d_in, const int* in_sizes, int n_in,
                              void* d_out, int out_size, void* d_ws,
                              size_t ws_size, hipStream_t stream) {
    const float* pred = (const float*)d_in[0];
    const float* tgt = (const float*)d_in[1];
    float* out = (float*)d_out;

    float* buf0 = (float*)d_ws;
    float* buf1 = buf0 + (size_t)BATCH * NPIX;
    unsigned* minb = (unsigned*)(buf1 + (size_t)BATCH * NPIX);
    unsigned* maxb = minb + NEROS * BATCH;
    double* sums = (double*)(maxb + NEROS * BATCH);
    unsigned* F = (unsigned*)(sums + NEROS * BATCH);
    unsigned* cnt = F + (size_t)NEROS * BATCH * FWPS;

    init_kernel<<<40, 256, 0, stream>>>(minb, maxb, sums, F, cnt);

    conv0_kernel<<<NT0, 512, 0, stream>>>(pred, tgt, buf0, F, &cnt[0], minb,
                                          maxb, sums);

    float* bufs[2] = {buf0, buf1};
    for (int k = 1; k < NEROS; ++k) {
        const float* src = bufs[(k - 1) & 1];
        float* dst = bufs[k & 1];
        convt_kernel<<<NTILES, 256, 0, stream>>>(
            src, dst, F + (size_t)(k - 1) * BATCH * FWPS,
            F + (size_t)k * BATCH * FWPS, &cnt[k - 1], &cnt[k],
            minb + (size_t)(k - 1) * BATCH, maxb + (size_t)(k - 1) * BATCH,
            minb + (size_t)k * BATCH, maxb + (size_t)k * BATCH,
            sums + (size_t)k * BATCH);
    }

    final_kernel<<<1, 64, 0, stream>>>(minb, maxb, sums, out);
}

// Round 7
// 137.643 us; speedup vs baseline: 1.0206x; 1.0206x over previous
//
#include <hip/hip_runtime.h>

#define BATCH 32
#define HH 1024
#define WW 1024
#define NPIX (HH * WW)
#define NEROS 10
#define TPS 64                // 16-row tiles per sample (tail kernel)
#define NTILES (BATCH * TPS)  // 2048 (tail grid)
#define FWPS 32               // flag words per sample: uint per 32 rows
#define NB0 512               // conv0: 32 samples x 16 slabs (64 rows each)
#define SLOTS 18              // circular LDS row slots (10 window + 8 staging)

__device__ __forceinline__ float4 ld4f(const float* p) {
    return *reinterpret_cast<const float4*>(p);
}

// ---------------- iteration 0: persistent pipelined bound+conv ----------------
// Block = 64-row slab, 512 threads (8 waves), walked as 8 tiles of 8 rows.
// 18-slot circular LDS row buffer (72 KB) -> 2 blocks/CU. Per tile: issue next
// tile's 16 global loads to regs (stay in flight across compute), compute from
// LDS, then drain+ds_write; ONE barrier per tile. Each input row is fetched
// exactly once. Reduce + flags + atomics once per block.
__global__ __launch_bounds__(512, 2) void conv0_kernel(
    const float* __restrict__ pred, const float* __restrict__ tgt,
    float* __restrict__ out, unsigned* __restrict__ Fout,
    unsigned* __restrict__ cntOut, unsigned* __restrict__ omin,
    unsigned* __restrict__ omax, double* __restrict__ osum) {
    int blk = blockIdx.x;
    blk = (blk & 7) * (NB0 >> 3) + (blk >> 3);  // XCD swizzle (512%8==0)
    const int s = blk >> 4, slab = blk & 15;
    const int r0 = slab << 6;  // first output row of slab
    const int tid = threadIdx.x, lane = tid & 63, w = tid >> 6;  // w: 0..7
    const size_t sbase = (size_t)s * NPIX;

    __shared__ float sb[SLOTS * 1024];  // 72 KB
    __shared__ float smn[8], smx[8], ssm[8];
    __shared__ unsigned sfa[8], sfb[8];

    // ---- initial fill: rows [r0-1, r0+9) -> slots (y+1)%18 ----
    {
        float4 pv[5], tv[5];
#pragma unroll
        for (int i = 0; i < 5; ++i) {
            const int idx = tid + 512 * i;  // 0..2559
            const int y = r0 - 1 + (idx >> 8);
            if (y >= 0 && y < HH) {
                const size_t g = sbase + (size_t)y * WW + ((idx & 255) << 2);
                pv[i] = ld4f(pred + g);
                tv[i] = ld4f(tgt + g);
            } else {
                pv[i] = make_float4(0.f, 0.f, 0.f, 0.f);
                tv[i] = make_float4(0.f, 0.f, 0.f, 0.f);
            }
        }
#pragma unroll
        for (int i = 0; i < 5; ++i) {
            const int idx = tid + 512 * i;
            const int y = r0 - 1 + (idx >> 8);
            const int slot = (int)((unsigned)(y + 1) % SLOTS);
            float4 b;
            b.x = (pv[i].x - tv[i].x) * (pv[i].x - tv[i].x);
            b.y = (pv[i].y - tv[i].y) * (pv[i].y - tv[i].y);
            b.z = (pv[i].z - tv[i].z) * (pv[i].z - tv[i].z);
            b.w = (pv[i].w - tv[i].w) * (pv[i].w - tv[i].w);
            *reinterpret_cast<float4*>(&sb[slot * 1024 + ((idx & 255) << 2)]) =
                b;
        }
    }
    __syncthreads();

    float lmin = 3.4e38f, lmax = 0.f, lsum = 0.f;
    unsigned fa = 0u, fb = 0u;  // nonzero-row bits for rows [r0, r0+64)

    for (int t = 0; t < 8; ++t) {
        const int rt = r0 + (t << 3);

        // (a) issue next tile's loads: rows [rt+9, rt+17) -> regs (in flight)
        float4 pv[4], tv[4];
        if (t < 7) {
#pragma unroll
            for (int i = 0; i < 4; ++i) {
                const int idx = tid + 512 * i;  // 0..2047
                const int y = rt + 9 + (idx >> 8);
                if (y < HH) {  // y >= r0+9 > 0 always
                    const size_t g =
                        sbase + (size_t)y * WW + ((idx & 255) << 2);
                    pv[i] = ld4f(pred + g);
                    tv[i] = ld4f(tgt + g);
                } else {
                    pv[i] = make_float4(0.f, 0.f, 0.f, 0.f);
                    tv[i] = make_float4(0.f, 0.f, 0.f, 0.f);
                }
            }
        }

        // (b) compute: wave w handles image row y = rt + w from LDS
        {
            const int y = rt + w;
            const int sU = (int)((unsigned)y % SLOTS);        // row y-1
            const int sC = (int)((unsigned)(y + 1) % SLOTS);  // row y
            const int sD = (int)((unsigned)(y + 2) % SLOTS);  // row y+1
            float O[16];
            bool nz = false;
#pragma unroll
            for (int q = 0; q < 4; ++q) {
                const int xw = (q << 8) + (lane << 2);
                const float4 U = *(const float4*)&sb[sU * 1024 + xw];
                const float4 Cc = *(const float4*)&sb[sC * 1024 + xw];
                const float4 D = *(const float4*)&sb[sD * 1024 + xw];
                float lf = __shfl_up(Cc.w, 1);
                if (lane == 0)
                    lf = (q > 0) ? sb[sC * 1024 + (q << 8) - 1] : 0.f;
                float rt2 = __shfl_down(Cc.x, 1);
                if (lane == 63)
                    rt2 = (q < 3) ? sb[sC * 1024 + (q << 8) + 256] : 0.f;
                const float cv[4] = {Cc.x, Cc.y, Cc.z, Cc.w};
                const float uv[4] = {U.x, U.y, U.z, U.w};
                const float dv[4] = {D.x, D.y, D.z, D.w};
                const float lvv[4] = {lf, Cc.x, Cc.y, Cc.z};
                const float rvv[4] = {Cc.y, Cc.z, Cc.w, rt2};
#pragma unroll
                for (int j = 0; j < 4; ++j) {
                    const float conv =
                        0.2f * (uv[j] + dv[j] + cv[j] + lvv[j] + rvv[j]);
                    const float er = fmaxf(conv - 0.5f, 0.f);
                    O[(q << 2) + j] = er;
                    lmin = fminf(lmin, er);
                    lmax = fmaxf(lmax, er);
                    lsum += er;
                    nz = nz || (er > 0.f);
                }
            }
            if (__ballot(nz) != 0ull) {  // wave-uniform: write whole row
                const size_t ob = sbase + (size_t)y * WW;
#pragma unroll
                for (int q = 0; q < 4; ++q)
                    *reinterpret_cast<float4*>(out + ob + (q << 8) +
                                               (lane << 2)) =
                        make_float4(O[q << 2], O[(q << 2) + 1],
                                    O[(q << 2) + 2], O[(q << 2) + 3]);
                const int ris = (t << 3) + w;  // row index in slab 0..63
                if (ris < 32)
                    fa |= 1u << ris;
                else
                    fb |= 1u << (ris - 32);
            }
        }

        // (c) drain loads + stage next tile's rows into their slots
        if (t < 7) {
#pragma unroll
            for (int i = 0; i < 4; ++i) {
                const int idx = tid + 512 * i;
                const int y = rt + 9 + (idx >> 8);
                const int slot = (int)((unsigned)(y + 1) % SLOTS);
                float4 b;
                b.x = (pv[i].x - tv[i].x) * (pv[i].x - tv[i].x);
                b.y = (pv[i].y - tv[i].y) * (pv[i].y - tv[i].y);
                b.z = (pv[i].z - tv[i].z) * (pv[i].z - tv[i].z);
                b.w = (pv[i].w - tv[i].w) * (pv[i].w - tv[i].w);
                *reinterpret_cast<float4*>(
                    &sb[slot * 1024 + ((idx & 255) << 2)]) = b;
            }
        }
        __syncthreads();
    }

    // ---- once-per-block reduce + flags + atomics ----
#pragma unroll
    for (int off = 32; off > 0; off >>= 1) {
        lmin = fminf(lmin, __shfl_down(lmin, off));
        lmax = fmaxf(lmax, __shfl_down(lmax, off));
        lsum += __shfl_down(lsum, off);
    }
    if (lane == 0) {
        smn[w] = lmin;
        smx[w] = lmax;
        ssm[w] = lsum;
        sfa[w] = fa;
        sfb[w] = fb;
    }
    __syncthreads();
    if (tid == 0) {
        unsigned fA = sfa[0], fB = sfb[0];
        float bmn = smn[0], bmx = smx[0], bsm = ssm[0];
#pragma unroll
        for (int i = 1; i < 8; ++i) {
            bmn = fminf(bmn, smn[i]);
            bmx = fmaxf(bmx, smx[i]);
            bsm += ssm[i];
            fA |= sfa[i];
            fB |= sfb[i];
        }
        // block exclusively owns these two flag words: plain stores
        Fout[s * FWPS + slab * 2] = fA;
        Fout[s * FWPS + slab * 2 + 1] = fB;
        if (fA | fB) atomicAdd(cntOut, 1u);
        atomicMin(&omin[s], __float_as_uint(bmn));
        if (bmx > 0.f) atomicMax(&omax[s], __float_as_uint(bmx));
        if (bsm > 0.f) atomicAdd(&osum[s], (double)bsm);
    }
}

// ---------------- iterations 1..9 (sparse tail) ----------------
// Block = 16-row tile, 4 waves; wave w owns rows [ry+4w, ry+4w+4); lane owns
// 16 px. Flag bit per row (uint per 32 rows): set = row has a nonzero.
// Unflagged rows are exact zeros and their memory is never read.
__global__ __launch_bounds__(256, 4) void convt_kernel(
    const float* __restrict__ in, float* __restrict__ out,
    const unsigned* __restrict__ Fprev, unsigned* __restrict__ Fout,
    const unsigned* __restrict__ cntPrev, unsigned* __restrict__ cntOut,
    const unsigned* __restrict__ pmin, const unsigned* __restrict__ pmax,
    unsigned* __restrict__ omin, unsigned* __restrict__ omax,
    double* __restrict__ osum) {
    if (*cntPrev == 0u) return;  // field died: absorbing state

    int blk = blockIdx.x;
    blk = (blk & 7) * (NTILES >> 3) + (blk >> 3);
    const int s = blk >> 6, ty = blk & 63, ry = ty << 4;
    const int tid = threadIdx.x, lane = tid & 63, w = tid >> 6;
    const int xb = lane << 4;
    const size_t sbase = (size_t)s * NPIX;

    // M: bit (i+1) = row ry+i flagged, i in [-1,16]
    const unsigned* Fs = Fprev + s * FWPS;
    const int w32 = ty >> 1, sh = (ty & 1) * 16;
    const unsigned cur = Fs[w32];
    unsigned M = ((cur >> sh) & 0xFFFFu) << 1;
    if (ty > 0)
        M |= (ty & 1) ? ((cur >> 15) & 1u) : ((Fs[w32 - 1] >> 31) & 1u);
    if (ty < TPS - 1) {
        const unsigned nb = (ty & 1) ? (Fs[w32 + 1] & 1u) : ((cur >> 16) & 1u);
        M |= nb << 17;
    }
    if (M == 0u) {  // nothing in reach: tile output exactly zero
        if (tid == 0) atomicMin(&omin[s], 0u);
        return;
    }

    float a = 1.f, cc = 0.f;
    {
        const float mn = __uint_as_float(pmin[s]);
        const float mx = __uint_as_float(pmax[s]);
        const float ptp = mx - mn;
        if (ptp > 0.f) { a = 1.f / ptp; cc = mn; }
    }

    const int r0 = w << 2;
    float A[16], B[16], C[16], O[16];

    auto loadRow = [&](int y, float* V) {
        const bool ok =
            (y >= 0 && y < HH) && (((M >> (y - ry + 1)) & 1u) != 0u);
        if (!ok) {
#pragma unroll
            for (int j = 0; j < 16; ++j) V[j] = 0.f;
            return;
        }
        const size_t idx = sbase + (size_t)y * WW + xb;
#pragma unroll
        for (int q = 0; q < 4; ++q) {
            const float4 v = ld4f(in + idx + 4 * q);
            V[4 * q + 0] = v.x;
            V[4 * q + 1] = v.y;
            V[4 * q + 2] = v.z;
            V[4 * q + 3] = v.w;
        }
    };

    loadRow(ry + r0 - 1, A);
    loadRow(ry + r0, B);

    float lmin = 3.4e38f, lmax = 0.f, lsum = 0.f;
    unsigned rowbits = 0u;

#pragma unroll
    for (int r = 0; r < 4; ++r) {
        const int y = ry + r0 + r;
        loadRow(y + 1, C);
        const bool act = (((M >> (r0 + r)) & 7u) != 0u);
        if (act) {
            float lfe = __shfl_up(B[15], 1);
            if (lane == 0) lfe = 0.f;
            float rte = __shfl_down(B[0], 1);
            if (lane == 63) rte = 0.f;
            const float vert =
                1.f + (y > 0 ? 1.f : 0.f) + (y < HH - 1 ? 1.f : 0.f);
            bool nz = false;
#pragma unroll
            for (int j = 0; j < 16; ++j) {
                const float lf = (j == 0) ? lfe : B[j - 1];
                const float rt = (j == 15) ? rte : B[j + 1];
                const float conv = 0.2f * (A[j] + C[j] + B[j] + lf + rt);
                const int x = xb + j;
                const float kf = 0.2f * (vert + (x > 0 ? 1.f : 0.f) +
                                         (x < WW - 1 ? 1.f : 0.f));
                const float dil = (conv - cc * kf) * a;
                const float er = fmaxf(dil - 0.5f, 0.f);
                O[j] = er;
                lmin = fminf(lmin, er);
                lmax = fmaxf(lmax, er);
                lsum += er;
                nz = nz || (er > 0.f);
            }
            if (__ballot(nz) != 0ull) {
                const size_t oidx = sbase + (size_t)y * WW + xb;
#pragma unroll
                for (int q = 0; q < 4; ++q)
                    *reinterpret_cast<float4*>(out + oidx + 4 * q) =
                        make_float4(O[4 * q], O[4 * q + 1], O[4 * q + 2],
                                    O[4 * q + 3]);
                rowbits |= 1u << (r0 + r);
            }
        } else {
            lmin = fminf(lmin, 0.f);
        }
#pragma unroll
        for (int j = 0; j < 16; ++j) {
            A[j] = B[j];
            B[j] = C[j];
        }
    }

#pragma unroll
    for (int off = 32; off > 0; off >>= 1) {
        lmin = fminf(lmin, __shfl_down(lmin, off));
        lmax = fmaxf(lmax, __shfl_down(lmax, off));
        lsum += __shfl_down(lsum, off);
    }
    __shared__ float smn[4], smx[4], ssm[4];
    __shared__ unsigned sfb[4];
    if (lane == 0) {
        smn[w] = lmin;
        smx[w] = lmax;
        ssm[w] = lsum;
        sfb[w] = rowbits;
    }
    __syncthreads();
    if (tid == 0) {
        const unsigned fmask = sfb[0] | sfb[1] | sfb[2] | sfb[3];
        float bmn = smn[0], bmx = smx[0], bsm = ssm[0];
#pragma unroll
        for (int i = 1; i < 4; ++i) {
            bmn = fminf(bmn, smn[i]);
            bmx = fmaxf(bmx, smx[i]);
            bsm += ssm[i];
        }
        if (fmask) {
            atomicOr(&Fout[s * FWPS + w32], fmask << sh);
            atomicAdd(cntOut, 1u);
        }
        atomicMin(&omin[s], __float_as_uint(bmn));
        if (bmx > 0.f) atomicMax(&omax[s], __float_as_uint(bmx));
        if (bsm > 0.f) atomicAdd(&osum[s], (double)bsm);
    }
}

__global__ void init_kernel(unsigned* __restrict__ minb,
                            unsigned* __restrict__ maxb,
                            double* __restrict__ sums,
                            unsigned* __restrict__ F,
                            unsigned* __restrict__ cnt) {
    const int i = blockIdx.x * blockDim.x + threadIdx.x;
    if (i < NEROS * BATCH) {
        minb[i] = 0x7f800000u;  // +inf
        maxb[i] = 0u;
        sums[i] = 0.0;
    }
    if (i < NEROS * BATCH * FWPS) F[i] = 0u;
    if (i < NEROS) cnt[i] = 0u;
}

__global__ void final_kernel(const unsigned* __restrict__ minb,
                             const unsigned* __restrict__ maxb,
                             const double* __restrict__ sums,
                             float* __restrict__ out) {
    const int s = threadIdx.x;
    double tot = 0.0;
    if (s < BATCH) {
        for (int k = 0; k < NEROS; ++k) {
            const float mn = __uint_as_float(minb[k * BATCH + s]);
            const float mx = __uint_as_float(maxb[k * BATCH + s]);
            const double sm = sums[k * BATCH + s];
            const float ptp = mx - mn;
            double v;
            if (ptp > 0.f)
                v = (sm - (double)NPIX * (double)mn) / (double)ptp;
            else
                v = sm;
            tot += (double)((k + 1) * (k + 1)) * v;
        }
    }
#pragma unroll
    for (int off = 32; off > 0; off >>= 1) tot += __shfl_down(tot, off);
    if (s == 0) out[0] = (float)(tot / ((double)BATCH * (double)NPIX));
}

extern "C" void kernel_launch(void* const* d_in, const int* in_sizes, int n_in,
                              void* d_out, int out_size, void* d_ws,
                              size_t ws_size, hipStream_t stream) {
    const float* pred = (const float*)d_in[0];
    const float* tgt = (const float*)d_in[1];
    float* out = (float*)d_out;

    float* buf0 = (float*)d_ws;
    float* buf1 = buf0 + (size_t)BATCH * NPIX;
    unsigned* minb = (unsigned*)(buf1 + (size_t)BATCH * NPIX);
    unsigned* maxb = minb + NEROS * BATCH;
    double* sums = (double*)(maxb + NEROS * BATCH);
    unsigned* F = (unsigned*)(sums + NEROS * BATCH);
    unsigned* cnt = F + (size_t)NEROS * BATCH * FWPS;

    init_kernel<<<40, 256, 0, stream>>>(minb, maxb, sums, F, cnt);

    conv0_kernel<<<NB0, 512, 0, stream>>>(pred, tgt, buf0, F, &cnt[0], minb,
                                          maxb, sums);

    float* bufs[2] = {buf0, buf1};
    for (int k = 1; k < NEROS; ++k) {
        const float* src = bufs[(k - 1) & 1];
        float* dst = bufs[k & 1];
        convt_kernel<<<NTILES, 256, 0, stream>>>(
            src, dst, F + (size_t)(k - 1) * BATCH * FWPS,
            F + (size_t)k * BATCH * FWPS, &cnt[k - 1], &cnt[k],
            minb + (size_t)(k - 1) * BATCH, maxb + (size_t)(k - 1) * BATCH,
            minb + (size_t)k * BATCH, maxb + (size_t)k * BATCH,
            sums + (size_t)k * BATCH);
    }

    final_kernel<<<1, 64, 0, stream>>>(minb, maxb, sums, out);
}